// Round 2
// baseline (433.409 us; speedup 1.0000x reference)
//
#include <hip/hip_runtime.h>
#include <math.h>

// Bayesian 2-layer LSTM (B=8192,T=100,I=24,H=64,H2=128) — two-kernel version.
//
// R7: wave-skew + paired-rcp pointwise + v_cvt_pk_bf16_f32.
// R6 profile: VALU 64%, MFMA 30%, occ 23% (2 waves/SIMD, W2 in AGPRs).
// Trans ops dominate VALU issue (120/thread/step). Changes:
// (1) Wave skew: waves 0-3 do L1->L2, waves 4-7 do L2->L1 (both read only
//     prev-buffer state) -> one group's MFMA phase overlaps the other's
//     trans phase. s_setprio(1) around L2 MFMA cluster (role diversity).
// (2) Paired reciprocals: all activations are rcp(1+exp2(k*x));
//     r=rcp(A*B), 1/A=r*B, 1/B=r*A -> 5 rcp -> 3 rcp per element.
// (3) v_cvt_pk_bf16_f32 (1 instr) replaces 4-op manual RNE f2bf for all
//     bf16 packing; fast softplus (exp2+log2) in sample_kernel.

typedef __attribute__((ext_vector_type(8))) short short8;   // 8 bf16
typedef __attribute__((ext_vector_type(4))) float f32x4;

#define MFMA16(a, b, c) __builtin_amdgcn_mfma_f32_16x16x32_bf16((a), (b), (c), 0, 0, 0)

// ---- d_ws layout (bytes) ----
// [0, 196608)        W2S : 12288 short8 frags, idx = (kk*4+g)*512 + tid
// [196608, 245760)   W1G : 3072 short8, u = slice*256+n (slice = kk*4+quad)
// [245760, 253284)   WF  : 1881 floats: b1[256] b2[512] fc1w[1024] fc2w[64]
//                          fc1b[8] fc2b[8] ow[8] ob[1]
#define WS_W1G_OFF 196608
#define WS_WF_OFF  245760

struct SampParams {
  const float* w1i[3]; const float* w1h[3]; const float* b1[3];
  const float* w2i[3]; const float* w2h[3]; const float* b2[3];
  const float* f1w[3]; const float* f1b[3];
  const float* f2w[3]; const float* f2b[3];
  const float* ow[3];  const float* ob[3];
  short* W2S; short* W1G; float* WF;
};

struct LstmParams {
  const float* input;
  const short* W2S; const short* W1G; const float* WF;
  float* out;
};

__device__ __forceinline__ float softplus_fast(float x) {
  // log(1+e^x) = ln2 * log2(1 + 2^(x*log2e))
  float e = __builtin_amdgcn_exp2f(1.44269504f * x);
  return 0.69314718f * __builtin_amdgcn_logf(1.0f + e);
}

__device__ __forceinline__ float samp(const float* const q[3], int idx) {
  return q[0][idx] + softplus_fast(q[1][idx]) * q[2][idx];
}

__device__ __forceinline__ short f2bf(float f) {
  unsigned u = __float_as_uint(f);
  unsigned r = (u + 0x7FFFu + ((u >> 16) & 1u)) >> 16;   // RNE
  return (short)r;
}

__device__ __forceinline__ unsigned cvt_pk_bf16(float lo, float hi) {
  unsigned r;
  asm("v_cvt_pk_bf16_f32 %0, %1, %2" : "=v"(r) : "v"(lo), "v"(hi));
  return r;
}

// One LSTM element: gates (i,f,g,o) -> new cell c, hidden h.
// All activations are rcp(1+exp2(k*x)); reciprocals paired:
// rcp(A)&rcp(B) via r=rcp(A*B): 1/A=r*B, 1/B=r*A.  5 exp2 + 3 rcp.
__device__ __forceinline__ void lstm_elem(float gi, float gf, float gg, float go,
                                          float& c, float& h) {
  float A = 1.0f + __builtin_amdgcn_exp2f(-1.44269504f * gi);   // 1/A = sig(i)
  float B = 1.0f + __builtin_amdgcn_exp2f(-1.44269504f * gf);   // 1/B = sig(f)
  float r = __builtin_amdgcn_rcpf(A * B);
  float si = r * B;
  float sf = r * A;
  float C = 1.0f + __builtin_amdgcn_exp2f(2.88539008f * gg);    // tanh(g)=1-2/C
  float D = 1.0f + __builtin_amdgcn_exp2f(-1.44269504f * go);   // 1/D = sig(o)
  float r2 = __builtin_amdgcn_rcpf(C * D);
  float tg = 1.0f - 2.0f * (r2 * D);
  float so = r2 * C;
  float cn = sf * c + si * tg;
  c = cn;
  float E = 1.0f + __builtin_amdgcn_exp2f(2.88539008f * cn);
  h = so * (1.0f - 2.0f * __builtin_amdgcn_rcpf(E));
}

// ---------------- kernel 1: sample all weights into d_ws ----------------
__global__ __launch_bounds__(256) void sample_kernel(SampParams p)
{
  int i = blockIdx.x * 256 + threadIdx.x;
  if (i < 12288) {
    int tid = i & 511, gg = (i >> 9) & 3, kk = i >> 11;
    int quad = (tid >> 4) & 3, col = tid & 15, v0 = (tid >> 6) * 16;
    int c = gg * 128 + v0 + col;
    short8 v;
#pragma unroll
    for (int j = 0; j < 8; ++j) {
      int k = kk * 32 + quad * 8 + j;
      float x = (k < 64) ? samp(p.w2i, k * 512 + c) : samp(p.w2h, (k - 64) * 512 + c);
      v[j] = f2bf(x);
    }
    *(short8*)&p.W2S[i * 8] = v;
  } else if (i < 15360) {
    int u = i - 12288;
    int slice = u >> 8, n = u & 255;
    int k0 = (slice >> 2) * 32 + (slice & 3) * 8;
    short8 v;
#pragma unroll
    for (int j = 0; j < 8; ++j) {
      int k = k0 + j;
      float x = 0.0f;
      if (k < 24)       x = samp(p.w1i, k * 256 + n);
      else if (k >= 32) x = samp(p.w1h, (k - 32) * 256 + n);
      v[j] = f2bf(x);
    }
    *(short8*)&p.W1G[u * 8] = v;
  } else if (i < 17241) {
    int u = i - 15360;
    float x;
    if (u < 256)       x = samp(p.b1,  u);
    else if (u < 768)  x = samp(p.b2,  u - 256);
    else if (u < 1792) x = samp(p.f1w, u - 768);
    else if (u < 1856) x = samp(p.f2w, u - 1792);
    else if (u < 1864) x = samp(p.f1b, u - 1856);
    else if (u < 1872) x = samp(p.f2b, u - 1864);
    else if (u < 1880) x = samp(p.ow,  u - 1872);
    else               x = samp(p.ob,  0);
    p.WF[u] = x;
  }
}

// ---------------- kernel 2: fused 2-layer LSTM + head ----------------
// LDS pool:
//   [0,49152)      W1L : W1cat bf16 (3072 short8)
//   [49152,62464)  A1  : 2 buf x (32 x 104 shorts) [x(24)|pad(8)|h1(64)]
//   [62464,79872)  A2  : 2 buf x (32 x 136 shorts) [h2(128)|pad]
// Head phase aliases [0,...) : H2 32x132 f32, FC1W, FC2W, FB1/FB2/OW/OB, X1, X2

__global__ __launch_bounds__(512, 2)
void blstm_kernel(LstmParams p)
{
  __shared__ __align__(16) unsigned char pool[79872];
  short* const W1L = (short*)pool;
  short* const A1b = (short*)(pool + 49152);   // 2 x 3328 shorts
  short* const A2b = (short*)(pool + 62464);   // 2 x 4352 shorts

  const int tid  = threadIdx.x;
  const int w    = tid >> 6;
  const int l    = tid & 63;
  const int quad = l >> 4;
  const int col  = l & 15;
  const int b0   = blockIdx.x * 32;

  const int wq = w & 3;             // layer1: n-group
  const int mh = w >> 2;            // layer1: m-half
  const int v0 = w * 16;            // layer2: unit base

  // W2 -> persistent registers/AGPRs (24 short8 = 96 regs). Occupancy is
  // grid-capped at 2 waves/SIMD, so regs up to 256 cost nothing.
  const short8* const W2v = (const short8*)p.W2S;
  short8 w2r[24];
#pragma unroll
  for (int f = 0; f < 24; ++f) w2r[f] = W2v[f * 512 + tid];

  // W1 global -> LDS (48 KB)
#pragma unroll
  for (int r = 0; r < 6; ++r) {
    short8 v = *(const short8*)&p.W1G[(r * 512 + tid) * 8];
    *(short8*)&W1L[(r * 512 + tid) * 8] = v;
  }

  float b1v[4], b2v[4];
#pragma unroll
  for (int g = 0; g < 4; ++g) b1v[g] = p.WF[g * 64 + wq * 16 + col];
#pragma unroll
  for (int g = 0; g < 4; ++g) b2v[g] = p.WF[256 + g * 128 + v0 + col];

  for (int i = tid; i < 6656; i += 512) A1b[i] = 0;   // both A1 buffers
  for (int i = tid; i < 8704; i += 512) A2b[i] = 0;   // both A2 buffers
  __syncthreads();

  // x_0 -> A1 buf0; hoisted per-thread x addressing (xr,xi loop-invariant)
  int xr = 0, xi = 0;
  const float* xptr = p.input;
  if (tid < 384) {
    int e = tid * 2; xr = e / 24; xi = e - xr * 24;
    const float* base = p.input + (size_t)(b0 + xr) * 2400 + xi;
    float2 xv = *(const float2*)base;
    *(unsigned*)&A1b[xr * 104 + xi] = cvt_pk_bf16(xv.x, xv.y);
    xptr = base + 24;                 // -> x_1
  }
  __syncthreads();

  float c1a[4]  = {0.f, 0.f, 0.f, 0.f};
  float c2a[2][4] = {{0.f,0.f,0.f,0.f},{0.f,0.f,0.f,0.f}};
  float hf2[2][4];

  const int a1rd = (mh * 16 + col) * 104;

  // Iteration j (j=0..100): computes h1_j (layer1 on [x_j|h1_{j-1}]) and
  // h2_{j-1} (layer2 on [h1_{j-1}|h2_{j-2}]). Reads buf (j&1), writes
  // buf (j&1)^1. Single barrier at iteration end. Waves 0-3 run L1 then
  // L2; waves 4-7 run L2 then L1 (both orders read only prev state) so
  // the MFMA-heavy L2 matmul of one group overlaps the trans-heavy
  // pointwise of the other.
  for (int j = 0; j <= 100; ++j) {
    const int pb = j & 1;
    const short* const A1r = A1b + pb * 3328;
    const short* const A2r = A2b + pb * 4352;
    short* const A1w = A1b + (pb ^ 1) * 3328;
    short* const A2w = A2b + (pb ^ 1) * 4352;

    const bool do_x = (j <= 98) && (tid < 384);
    float2 xv;
    if (do_x) xv = *(const float2*)xptr;   // x_{j+1}

    auto do_l1 = [&]() {
      // ---- layer 1 matmul: gates1_j ----
      short8 aA0 = *(const short8*)&A1r[a1rd +      quad * 8];
      short8 aA1 = *(const short8*)&A1r[a1rd + 32 + quad * 8];
      short8 aA2 = *(const short8*)&A1r[a1rd + 64 + quad * 8];
      f32x4 g1[4];
#pragma unroll
      for (int g = 0; g < 4; ++g) {
        f32x4 acc = (f32x4){b1v[g], b1v[g], b1v[g], b1v[g]};
        acc = MFMA16(aA0, *(const short8*)&W1L[(((0 * 4 + quad) << 8) + g * 64 + wq * 16 + col) * 8], acc);
        acc = MFMA16(aA1, *(const short8*)&W1L[(((1 * 4 + quad) << 8) + g * 64 + wq * 16 + col) * 8], acc);
        acc = MFMA16(aA2, *(const short8*)&W1L[(((2 * 4 + quad) << 8) + g * 64 + wq * 16 + col) * 8], acc);
        g1[g] = acc;
      }
      // ---- layer 1 pointwise -> h1_j into next buffer ----
      float h1v[4];
#pragma unroll
      for (int i = 0; i < 4; ++i)
        lstm_elem(g1[0][i], g1[1][i], g1[2][i], g1[3][i], c1a[i], h1v[i]);
      {
        int base = (mh * 16 + quad * 4) * 104 + 32 + wq * 16 + col;
        unsigned pkA = cvt_pk_bf16(h1v[0], h1v[1]);
        unsigned pkB = cvt_pk_bf16(h1v[2], h1v[3]);
        A1w[base]       = (short)pkA;
        A1w[base + 104] = (short)(pkA >> 16);
        A1w[base + 208] = (short)pkB;
        A1w[base + 312] = (short)(pkB >> 16);
      }
      if (do_x)
        *(unsigned*)&A1w[xr * 104 + xi] = cvt_pk_bf16(xv.x, xv.y);
    };

    auto do_l2 = [&]() {
      // ---- layer 2 matmul: gates2_{j-1} (B-operand from registers) ----
      f32x4 g2[2][4];
#pragma unroll
      for (int g = 0; g < 4; ++g) {
        g2[0][g] = (f32x4){b2v[g], b2v[g], b2v[g], b2v[g]};
        g2[1][g] = g2[0][g];
      }
      __builtin_amdgcn_s_setprio(1);
#pragma unroll
      for (int kk = 0; kk < 6; ++kk) {
        short8 a0, a1f;
        if (kk < 2) {
          a0  = *(const short8*)&A1r[      col  * 104 + 32 + kk * 32 + quad * 8];
          a1f = *(const short8*)&A1r[(16 + col) * 104 + 32 + kk * 32 + quad * 8];
        } else {
          int o = (kk - 2) * 32 + quad * 8;
          a0  = *(const short8*)&A2r[      col  * 136 + o];
          a1f = *(const short8*)&A2r[(16 + col) * 136 + o];
        }
#pragma unroll
        for (int g = 0; g < 4; ++g) {
          g2[0][g] = MFMA16(a0,  w2r[kk * 4 + g], g2[0][g]);
          g2[1][g] = MFMA16(a1f, w2r[kk * 4 + g], g2[1][g]);
        }
      }
      __builtin_amdgcn_s_setprio(0);
      // ---- layer 2 pointwise -> h2_{j-1} (skip j=0) ----
      if (j) {
        int u2 = v0 + col;
#pragma unroll
        for (int mi = 0; mi < 2; ++mi) {
          float hv[4];
#pragma unroll
          for (int i = 0; i < 4; ++i) {
            lstm_elem(g2[mi][0][i], g2[mi][1][i], g2[mi][2][i], g2[mi][3][i],
                      c2a[mi][i], hv[i]);
            hf2[mi][i] = hv[i];
          }
          unsigned pkA = cvt_pk_bf16(hv[0], hv[1]);
          unsigned pkB = cvt_pk_bf16(hv[2], hv[3]);
          int base = (mi * 16 + quad * 4) * 136 + u2;
          A2w[base]       = (short)pkA;
          A2w[base + 136] = (short)(pkA >> 16);
          A2w[base + 272] = (short)pkB;
          A2w[base + 408] = (short)(pkB >> 16);
        }
      }
    };

    if (w < 4) { do_l1(); do_l2(); }
    else       { do_l2(); do_l1(); }

    __syncthreads();   // writes to buf pb^1 visible; reads of buf pb done
    xptr += 24;
  }

  // ---- head (fp32), aliased over W1L region ----
  float* const H2   = (float*)pool;                 // 32 x 132
  float* const FC1W = (float*)(pool + 16896);
  float* const FC2W = (float*)(pool + 20992);
  float* const FB1  = (float*)(pool + 21248);
  float* const FB2  = (float*)(pool + 21280);
  float* const OWp  = (float*)(pool + 21312);
  float* const OBp  = (float*)(pool + 21344);
  float* const X1   = (float*)(pool + 21376);
  float* const X2   = (float*)(pool + 22400);

  {
    int u2 = v0 + col;
#pragma unroll
    for (int mi = 0; mi < 2; ++mi)
#pragma unroll
      for (int i = 0; i < 4; ++i) {
        int row = mi * 16 + quad * 4 + i;
        H2[row * 132 + u2] = hf2[mi][i];   // h2_99
      }
  }
  for (int i = tid; i < 1024; i += 512) FC1W[i] = p.WF[768 + i];
  if (tid < 64)               FC2W[tid]     = p.WF[1792 + tid];
  if (tid >= 64 && tid < 72)  FB1[tid - 64] = p.WF[1856 + tid - 64];
  if (tid >= 72 && tid < 80)  FB2[tid - 72] = p.WF[1864 + tid - 72];
  if (tid >= 80 && tid < 88)  OWp[tid - 80] = p.WF[1872 + tid - 80];
  if (tid == 88)              OBp[0]        = p.WF[1880];
  __syncthreads();

  if (tid < 256) {
    int row = tid >> 3, o = tid & 7;
    float s = FB1[o];
#pragma unroll 8
    for (int k = 0; k < 128; ++k) s += H2[row * 132 + k] * FC1W[o * 128 + k];
    X1[tid] = fmaxf(s, 0.0f);
  }
  __syncthreads();
  if (tid < 256) {
    int row = tid >> 3, o = tid & 7;
    float s = FB2[o];
#pragma unroll
    for (int k = 0; k < 8; ++k) s += X1[row * 8 + k] * FC2W[o * 8 + k];
    X2[tid] = fmaxf(s, 0.0f);
  }
  __syncthreads();
  if (tid < 32) {
    float s = OBp[0];
#pragma unroll
    for (int k = 0; k < 8; ++k) s += X2[tid * 8 + k] * OWp[k];
    p.out[b0 + tid] = s;
  }
}

extern "C" void kernel_launch(void* const* d_in, const int* in_sizes, int n_in,
                              void* d_out, int out_size, void* d_ws, size_t ws_size,
                              hipStream_t stream)
{
  (void)in_sizes; (void)n_in; (void)ws_size; (void)out_size;

  SampParams sp;
  const float** grp[12] = { sp.w1i, sp.w1h, sp.b1, sp.w2i, sp.w2h, sp.b2,
                            sp.f1w, sp.f1b, sp.f2w, sp.f2b, sp.ow, sp.ob };
  int idx = 1;
  for (int t = 0; t < 12; ++t)
    for (int j = 0; j < 3; ++j)
      grp[t][j] = (const float*)d_in[idx++];
  sp.W2S = (short*)d_ws;
  sp.W1G = (short*)((char*)d_ws + WS_W1G_OFF);
  sp.WF  = (float*)((char*)d_ws + WS_WF_OFF);

  LstmParams bp;
  bp.input = (const float*)d_in[0];
  bp.W2S = (const short*)d_ws;
  bp.W1G = (const short*)((char*)d_ws + WS_W1G_OFF);
  bp.WF  = (const float*)((char*)d_ws + WS_WF_OFF);
  bp.out = (float*)d_out;

  sample_kernel<<<dim3(68), dim3(256), 0, stream>>>(sp);
  blstm_kernel<<<dim3(256), dim3(512), 0, stream>>>(bp);
}

// Round 3
// 400.009 us; speedup vs baseline: 1.0835x; 1.0835x over previous
//
#include <hip/hip_runtime.h>
#include <math.h>

// Bayesian 2-layer LSTM (B=8192,T=100,I=24,H=64,H2=128) — two-kernel version.
//
// R8: R6 control structure (303 us) + R7's VALU reductions, minus R7's
// wave-skew/setprio (measured regression: skew cost > overlap gain in a
// lockstep-barrier loop).
// Kept: (a) paired-reciprocal lstm_elem: rcp(A)&rcp(B) via r=rcp(A*B)
//       -> 5 exp2 + 3 rcp per element (vs 10 trans);
//       (b) v_cvt_pk_bf16_f32 single-instr bf16 packing.
// New:  (c) j=0 peeled (no 'if(j)' in steady state, skips dead j=0 L2
//       matmul); main loop j=1..100 unrolled x2 so double-buffer pointers
//       are compile-time per half -> all LDS addresses loop-invariant.

typedef __attribute__((ext_vector_type(8))) short short8;   // 8 bf16
typedef __attribute__((ext_vector_type(4))) float f32x4;

#define MFMA16(a, b, c) __builtin_amdgcn_mfma_f32_16x16x32_bf16((a), (b), (c), 0, 0, 0)

// ---- d_ws layout (bytes) ----
// [0, 196608)        W2S : 12288 short8 frags, idx = (kk*4+g)*512 + tid
// [196608, 245760)   W1G : 3072 short8, u = slice*256+n (slice = kk*4+quad)
// [245760, 253284)   WF  : 1881 floats: b1[256] b2[512] fc1w[1024] fc2w[64]
//                          fc1b[8] fc2b[8] ow[8] ob[1]
#define WS_W1G_OFF 196608
#define WS_WF_OFF  245760

struct SampParams {
  const float* w1i[3]; const float* w1h[3]; const float* b1[3];
  const float* w2i[3]; const float* w2h[3]; const float* b2[3];
  const float* f1w[3]; const float* f1b[3];
  const float* f2w[3]; const float* f2b[3];
  const float* ow[3];  const float* ob[3];
  short* W2S; short* W1G; float* WF;
};

struct LstmParams {
  const float* input;
  const short* W2S; const short* W1G; const float* WF;
  float* out;
};

__device__ __forceinline__ float softplus_fast(float x) {
  // log(1+e^x) = ln2 * log2(1 + 2^(x*log2e))
  float e = __builtin_amdgcn_exp2f(1.44269504f * x);
  return 0.69314718f * __builtin_amdgcn_logf(1.0f + e);
}

__device__ __forceinline__ float samp(const float* const q[3], int idx) {
  return q[0][idx] + softplus_fast(q[1][idx]) * q[2][idx];
}

__device__ __forceinline__ short f2bf(float f) {
  unsigned u = __float_as_uint(f);
  unsigned r = (u + 0x7FFFu + ((u >> 16) & 1u)) >> 16;   // RNE
  return (short)r;
}

__device__ __forceinline__ unsigned cvt_pk_bf16(float lo, float hi) {
  unsigned r;
  asm("v_cvt_pk_bf16_f32 %0, %1, %2" : "=v"(r) : "v"(lo), "v"(hi));
  return r;
}

// One LSTM element: gates (i,f,g,o) -> new cell c, hidden h.
// All activations are rcp(1+exp2(k*x)); reciprocals paired:
// rcp(A)&rcp(B) via r=rcp(A*B): 1/A=r*B, 1/B=r*A.  5 exp2 + 3 rcp.
__device__ __forceinline__ void lstm_elem(float gi, float gf, float gg, float go,
                                          float& c, float& h) {
  float A = 1.0f + __builtin_amdgcn_exp2f(-1.44269504f * gi);   // 1/A = sig(i)
  float B = 1.0f + __builtin_amdgcn_exp2f(-1.44269504f * gf);   // 1/B = sig(f)
  float r = __builtin_amdgcn_rcpf(A * B);
  float si = r * B;
  float sf = r * A;
  float C = 1.0f + __builtin_amdgcn_exp2f(2.88539008f * gg);    // tanh(g)=1-2/C
  float D = 1.0f + __builtin_amdgcn_exp2f(-1.44269504f * go);   // 1/D = sig(o)
  float r2 = __builtin_amdgcn_rcpf(C * D);
  float tg = 1.0f - 2.0f * (r2 * D);
  float so = r2 * C;
  float cn = sf * c + si * tg;
  c = cn;
  float E = 1.0f + __builtin_amdgcn_exp2f(2.88539008f * cn);
  h = so * (1.0f - 2.0f * __builtin_amdgcn_rcpf(E));
}

// ---------------- kernel 1: sample all weights into d_ws ----------------
__global__ __launch_bounds__(256) void sample_kernel(SampParams p)
{
  int i = blockIdx.x * 256 + threadIdx.x;
  if (i < 12288) {
    int tid = i & 511, gg = (i >> 9) & 3, kk = i >> 11;
    int quad = (tid >> 4) & 3, col = tid & 15, v0 = (tid >> 6) * 16;
    int c = gg * 128 + v0 + col;
    short8 v;
#pragma unroll
    for (int j = 0; j < 8; ++j) {
      int k = kk * 32 + quad * 8 + j;
      float x = (k < 64) ? samp(p.w2i, k * 512 + c) : samp(p.w2h, (k - 64) * 512 + c);
      v[j] = f2bf(x);
    }
    *(short8*)&p.W2S[i * 8] = v;
  } else if (i < 15360) {
    int u = i - 12288;
    int slice = u >> 8, n = u & 255;
    int k0 = (slice >> 2) * 32 + (slice & 3) * 8;
    short8 v;
#pragma unroll
    for (int j = 0; j < 8; ++j) {
      int k = k0 + j;
      float x = 0.0f;
      if (k < 24)       x = samp(p.w1i, k * 256 + n);
      else if (k >= 32) x = samp(p.w1h, (k - 32) * 256 + n);
      v[j] = f2bf(x);
    }
    *(short8*)&p.W1G[u * 8] = v;
  } else if (i < 17241) {
    int u = i - 15360;
    float x;
    if (u < 256)       x = samp(p.b1,  u);
    else if (u < 768)  x = samp(p.b2,  u - 256);
    else if (u < 1792) x = samp(p.f1w, u - 768);
    else if (u < 1856) x = samp(p.f2w, u - 1792);
    else if (u < 1864) x = samp(p.f1b, u - 1856);
    else if (u < 1872) x = samp(p.f2b, u - 1864);
    else if (u < 1880) x = samp(p.ow,  u - 1872);
    else               x = samp(p.ob,  0);
    p.WF[u] = x;
  }
}

// ---------------- kernel 2: fused 2-layer LSTM + head ----------------
// LDS pool:
//   [0,49152)      W1L : W1cat bf16 (3072 short8)
//   [49152,62464)  A1  : 2 buf x (32 x 104 shorts) [x(24)|pad(8)|h1(64)]
//   [62464,79872)  A2  : 2 buf x (32 x 136 shorts) [h2(128)|pad]
// Head phase aliases [0,...) : H2 32x132 f32, FC1W, FC2W, FB1/FB2/OW/OB, X1, X2

__global__ __launch_bounds__(512, 2)
void blstm_kernel(LstmParams p)
{
  __shared__ __align__(16) unsigned char pool[79872];
  short* const W1L = (short*)pool;
  short* const A1b = (short*)(pool + 49152);   // 2 x 3328 shorts
  short* const A2b = (short*)(pool + 62464);   // 2 x 4352 shorts

  const int tid  = threadIdx.x;
  const int w    = tid >> 6;
  const int l    = tid & 63;
  const int quad = l >> 4;
  const int col  = l & 15;
  const int b0   = blockIdx.x * 32;

  const int wq = w & 3;             // layer1: n-group
  const int mh = w >> 2;            // layer1: m-half
  const int v0 = w * 16;            // layer2: unit base

  // W2 -> persistent registers/AGPRs (24 short8 = 96 regs). Occupancy is
  // grid-capped at 2 waves/SIMD, so regs up to 256 cost nothing.
  const short8* const W2v = (const short8*)p.W2S;
  short8 w2r[24];
#pragma unroll
  for (int f = 0; f < 24; ++f) w2r[f] = W2v[f * 512 + tid];

  // W1 global -> LDS (48 KB)
#pragma unroll
  for (int r = 0; r < 6; ++r) {
    short8 v = *(const short8*)&p.W1G[(r * 512 + tid) * 8];
    *(short8*)&W1L[(r * 512 + tid) * 8] = v;
  }

  float b1v[4], b2v[4];
#pragma unroll
  for (int g = 0; g < 4; ++g) b1v[g] = p.WF[g * 64 + wq * 16 + col];
#pragma unroll
  for (int g = 0; g < 4; ++g) b2v[g] = p.WF[256 + g * 128 + v0 + col];

  for (int i = tid; i < 6656; i += 512) A1b[i] = 0;   // both A1 buffers
  for (int i = tid; i < 8704; i += 512) A2b[i] = 0;   // both A2 buffers
  __syncthreads();

  // x_0 -> A1 buf0; hoisted per-thread x addressing (xr,xi loop-invariant)
  int xr = 0, xi = 0;
  const bool xln = tid < 384;
  const float* xptr = p.input;
  if (xln) {
    int e = tid * 2; xr = e / 24; xi = e - xr * 24;
    const float* base = p.input + (size_t)(b0 + xr) * 2400 + xi;
    float2 xv = *(const float2*)base;
    *(unsigned*)&A1b[xr * 104 + xi] = cvt_pk_bf16(xv.x, xv.y);
    xptr = base + 24;                 // -> x_1
  }
  __syncthreads();

  float c1a[4]  = {0.f, 0.f, 0.f, 0.f};
  float c2a[2][4] = {{0.f,0.f,0.f,0.f},{0.f,0.f,0.f,0.f}};
  float hf2[2][4];

  const int a1rd = (mh * 16 + col) * 104;

  // Full step: layer1 (gates1 on [x|h1_prev]) -> pointwise -> layer2
  // (gates2 on [h1_prev|h2_prev]) -> pointwise. Reads A1r/A2r, writes
  // A1w/A2w. All pointers compile-time constant at each call site.
  auto step = [&](const short* __restrict__ A1r, const short* __restrict__ A2r,
                  short* __restrict__ A1w, short* __restrict__ A2w, bool dox) {
    const bool do_x = dox && xln;
    float2 xv;
    if (do_x) xv = *(const float2*)xptr;   // x_{j+1}

    // ---- layer 1 matmul: gates1 ----
    short8 aA0 = *(const short8*)&A1r[a1rd +      quad * 8];
    short8 aA1 = *(const short8*)&A1r[a1rd + 32 + quad * 8];
    short8 aA2 = *(const short8*)&A1r[a1rd + 64 + quad * 8];
    f32x4 g1[4];
#pragma unroll
    for (int g = 0; g < 4; ++g) {
      f32x4 acc = (f32x4){b1v[g], b1v[g], b1v[g], b1v[g]};
      acc = MFMA16(aA0, *(const short8*)&W1L[(((0 * 4 + quad) << 8) + g * 64 + wq * 16 + col) * 8], acc);
      acc = MFMA16(aA1, *(const short8*)&W1L[(((1 * 4 + quad) << 8) + g * 64 + wq * 16 + col) * 8], acc);
      acc = MFMA16(aA2, *(const short8*)&W1L[(((2 * 4 + quad) << 8) + g * 64 + wq * 16 + col) * 8], acc);
      g1[g] = acc;
    }

    // ---- layer 1 pointwise -> h1 into next buffer ----
    {
      float h1v[4];
#pragma unroll
      for (int i = 0; i < 4; ++i)
        lstm_elem(g1[0][i], g1[1][i], g1[2][i], g1[3][i], c1a[i], h1v[i]);
      int base = (mh * 16 + quad * 4) * 104 + 32 + wq * 16 + col;
      unsigned pkA = cvt_pk_bf16(h1v[0], h1v[1]);
      unsigned pkB = cvt_pk_bf16(h1v[2], h1v[3]);
      A1w[base]       = (short)pkA;
      A1w[base + 104] = (short)(pkA >> 16);
      A1w[base + 208] = (short)pkB;
      A1w[base + 312] = (short)(pkB >> 16);
    }
    if (do_x)
      *(unsigned*)&A1w[xr * 104 + xi] = cvt_pk_bf16(xv.x, xv.y);

    // ---- layer 2 matmul: gates2 (B-operand from registers) ----
    f32x4 g2[2][4];
#pragma unroll
    for (int g = 0; g < 4; ++g) {
      g2[0][g] = (f32x4){b2v[g], b2v[g], b2v[g], b2v[g]};
      g2[1][g] = g2[0][g];
    }
#pragma unroll
    for (int kk = 0; kk < 6; ++kk) {
      short8 a0, a1f;
      if (kk < 2) {
        a0  = *(const short8*)&A1r[      col  * 104 + 32 + kk * 32 + quad * 8];
        a1f = *(const short8*)&A1r[(16 + col) * 104 + 32 + kk * 32 + quad * 8];
      } else {
        int o = (kk - 2) * 32 + quad * 8;
        a0  = *(const short8*)&A2r[      col  * 136 + o];
        a1f = *(const short8*)&A2r[(16 + col) * 136 + o];
      }
#pragma unroll
      for (int g = 0; g < 4; ++g) {
        g2[0][g] = MFMA16(a0,  w2r[kk * 4 + g], g2[0][g]);
        g2[1][g] = MFMA16(a1f, w2r[kk * 4 + g], g2[1][g]);
      }
    }

    // ---- layer 2 pointwise -> h2 into next buffer ----
    {
      int u2 = v0 + col;
#pragma unroll
      for (int mi = 0; mi < 2; ++mi) {
        float hv[4];
#pragma unroll
        for (int i = 0; i < 4; ++i) {
          lstm_elem(g2[mi][0][i], g2[mi][1][i], g2[mi][2][i], g2[mi][3][i],
                    c2a[mi][i], hv[i]);
          hf2[mi][i] = hv[i];
        }
        unsigned pkA = cvt_pk_bf16(hv[0], hv[1]);
        unsigned pkB = cvt_pk_bf16(hv[2], hv[3]);
        int base = (mi * 16 + quad * 4) * 136 + u2;
        A2w[base]       = (short)pkA;
        A2w[base + 136] = (short)(pkA >> 16);
        A2w[base + 272] = (short)pkB;
        A2w[base + 408] = (short)(pkB >> 16);
      }
    }
  };

  short* const A1_0 = A1b;            short* const A1_1 = A1b + 3328;
  short* const A2_0 = A2b;            short* const A2_1 = A2b + 4352;

  // ---- j=0 peeled: layer1 only (h1_0), x_1 prefetch; L2 state is zeros ----
  {
    float2 xv;
    if (xln) xv = *(const float2*)xptr;
    short8 aA0 = *(const short8*)&A1_0[a1rd +      quad * 8];
    short8 aA1 = *(const short8*)&A1_0[a1rd + 32 + quad * 8];
    short8 aA2 = *(const short8*)&A1_0[a1rd + 64 + quad * 8];
    f32x4 g1[4];
#pragma unroll
    for (int g = 0; g < 4; ++g) {
      f32x4 acc = (f32x4){b1v[g], b1v[g], b1v[g], b1v[g]};
      acc = MFMA16(aA0, *(const short8*)&W1L[(((0 * 4 + quad) << 8) + g * 64 + wq * 16 + col) * 8], acc);
      acc = MFMA16(aA1, *(const short8*)&W1L[(((1 * 4 + quad) << 8) + g * 64 + wq * 16 + col) * 8], acc);
      acc = MFMA16(aA2, *(const short8*)&W1L[(((2 * 4 + quad) << 8) + g * 64 + wq * 16 + col) * 8], acc);
      g1[g] = acc;
    }
    float h1v[4];
#pragma unroll
    for (int i = 0; i < 4; ++i)
      lstm_elem(g1[0][i], g1[1][i], g1[2][i], g1[3][i], c1a[i], h1v[i]);
    int base = (mh * 16 + quad * 4) * 104 + 32 + wq * 16 + col;
    unsigned pkA = cvt_pk_bf16(h1v[0], h1v[1]);
    unsigned pkB = cvt_pk_bf16(h1v[2], h1v[3]);
    A1_1[base]       = (short)pkA;
    A1_1[base + 104] = (short)(pkA >> 16);
    A1_1[base + 208] = (short)pkB;
    A1_1[base + 312] = (short)(pkB >> 16);
    if (xln)
      *(unsigned*)&A1_1[xr * 104 + xi] = cvt_pk_bf16(xv.x, xv.y);
    __syncthreads();
    xptr += 24;
  }

  // ---- main loop: j = 1..100, unrolled x2 (buffer roles compile-time) ----
  for (int jj = 1; jj <= 99; jj += 2) {
    // j = jj (odd): read buf1, write buf0
    step(A1_1, A2_1, A1_0, A2_0, jj <= 98);
    __syncthreads();
    xptr += 24;
    // j = jj+1 (even): read buf0, write buf1
    step(A1_0, A2_0, A1_1, A2_1, jj + 1 <= 98);
    __syncthreads();
    xptr += 24;
  }

  // ---- head (fp32), aliased over W1L region ----
  float* const H2   = (float*)pool;                 // 32 x 132
  float* const FC1W = (float*)(pool + 16896);
  float* const FC2W = (float*)(pool + 20992);
  float* const FB1  = (float*)(pool + 21248);
  float* const FB2  = (float*)(pool + 21280);
  float* const OWp  = (float*)(pool + 21312);
  float* const OBp  = (float*)(pool + 21344);
  float* const X1   = (float*)(pool + 21376);
  float* const X2   = (float*)(pool + 22400);

  {
    int u2 = v0 + col;
#pragma unroll
    for (int mi = 0; mi < 2; ++mi)
#pragma unroll
      for (int i = 0; i < 4; ++i) {
        int row = mi * 16 + quad * 4 + i;
        H2[row * 132 + u2] = hf2[mi][i];   // h2_99
      }
  }
  for (int i = tid; i < 1024; i += 512) FC1W[i] = p.WF[768 + i];
  if (tid < 64)               FC2W[tid]     = p.WF[1792 + tid];
  if (tid >= 64 && tid < 72)  FB1[tid - 64] = p.WF[1856 + tid - 64];
  if (tid >= 72 && tid < 80)  FB2[tid - 72] = p.WF[1864 + tid - 72];
  if (tid >= 80 && tid < 88)  OWp[tid - 80] = p.WF[1872 + tid - 80];
  if (tid == 88)              OBp[0]        = p.WF[1880];
  __syncthreads();

  if (tid < 256) {
    int row = tid >> 3, o = tid & 7;
    float s = FB1[o];
#pragma unroll 8
    for (int k = 0; k < 128; ++k) s += H2[row * 132 + k] * FC1W[o * 128 + k];
    X1[tid] = fmaxf(s, 0.0f);
  }
  __syncthreads();
  if (tid < 256) {
    int row = tid >> 3, o = tid & 7;
    float s = FB2[o];
#pragma unroll
    for (int k = 0; k < 8; ++k) s += X1[row * 8 + k] * FC2W[o * 8 + k];
    X2[tid] = fmaxf(s, 0.0f);
  }
  __syncthreads();
  if (tid < 32) {
    float s = OBp[0];
#pragma unroll
    for (int k = 0; k < 8; ++k) s += X2[tid * 8 + k] * OWp[k];
    p.out[b0 + tid] = s;
  }
}

extern "C" void kernel_launch(void* const* d_in, const int* in_sizes, int n_in,
                              void* d_out, int out_size, void* d_ws, size_t ws_size,
                              hipStream_t stream)
{
  (void)in_sizes; (void)n_in; (void)ws_size; (void)out_size;

  SampParams sp;
  const float** grp[12] = { sp.w1i, sp.w1h, sp.b1, sp.w2i, sp.w2h, sp.b2,
                            sp.f1w, sp.f1b, sp.f2w, sp.f2b, sp.ow, sp.ob };
  int idx = 1;
  for (int t = 0; t < 12; ++t)
    for (int j = 0; j < 3; ++j)
      grp[t][j] = (const float*)d_in[idx++];
  sp.W2S = (short*)d_ws;
  sp.W1G = (short*)((char*)d_ws + WS_W1G_OFF);
  sp.WF  = (float*)((char*)d_ws + WS_WF_OFF);

  LstmParams bp;
  bp.input = (const float*)d_in[0];
  bp.W2S = (const short*)d_ws;
  bp.W1G = (const short*)((char*)d_ws + WS_W1G_OFF);
  bp.WF  = (const float*)((char*)d_ws + WS_WF_OFF);
  bp.out = (float*)d_out;

  sample_kernel<<<dim3(68), dim3(256), 0, stream>>>(sp);
  blstm_kernel<<<dim3(256), dim3(512), 0, stream>>>(bp);
}